// Round 6
// baseline (488.787 us; speedup 1.0000x reference)
//
#include <hip/hip_runtime.h>
#include <hip/hip_bf16.h>

// Problem constants
constexpr int       DIM        = 128;
constexpr long long CN         = 131073;               // 1 + QUEUE_K
constexpr long long OUT_ELEMS  = 256LL * 131073LL;     // 33554688
constexpr long long PROBS_OFF  = OUT_ELEMS;
constexpr long long MEMOUT_OFF = OUT_ELEMS + 1;
constexpr long long MEM_ELEMS  = 131072LL * 128LL;     // 16777216

constexpr float SCL = 20.60992915555662f;              // log2(e)/0.07

// ws layout (float indices)
constexpr int WS_CTR   = 8;      // 1 uint (barrier counter)
constexpr int WS_KMEAN = 272;    // 64*128 floats
constexpr int WS_ROWP  = 8464;   // 32 slices x 256 floats

constexpr int GRID   = 512;      // 2 blocks/CU x 256 CU — co-residency guaranteed by launch_bounds(256,2)
constexpr int NTILES = 8;        // 8 tiles x 32 cols = 256 cols per block; 512*256 = 131072

typedef __attribute__((ext_vector_type(8))) short  short8v;
typedef __attribute__((ext_vector_type(4))) float  f32x4;
typedef __attribute__((ext_vector_type(4), aligned(4))) float f32x4u;  // 4B-aligned vec4

__device__ __forceinline__ unsigned short f2bf(float x) {
  unsigned u = __float_as_uint(x);
  u += 0x7fffu + ((u >> 16) & 1u);   // RNE
  return (unsigned short)(u >> 16);
}

__device__ __forceinline__ short8v pack8(float4 a, float4 b) {
  short8v h;
  h[0] = (short)f2bf(a.x); h[1] = (short)f2bf(a.y);
  h[2] = (short)f2bf(a.z); h[3] = (short)f2bf(a.w);
  h[4] = (short)f2bf(b.x); h[5] = (short)f2bf(b.y);
  h[6] = (short)f2bf(b.z); h[7] = (short)f2bf(b.w);
  return h;
}

__global__ __launch_bounds__(256, 2) void k_mega(const float* __restrict__ qg,
                                                 const float* __restrict__ kg,
                                                 const float* __restrict__ memv,
                                                 float* __restrict__ ws,
                                                 float* __restrict__ out) {
  const int b = blockIdx.x, t = threadIdx.x;
  const int lane = t & 63, wave = t >> 6, g = lane >> 4, nlo = lane & 15;
  __shared__ float sh_s;          // exp(l_pos/T) for row b (blocks < 256)
  __shared__ float sh_rs[256];    // per-row full sums
  __shared__ float sh_red[256];   // reduction scratch

  // ---- q fragments: f32 -> bf16 in-reg; LIVE ACROSS THE BARRIER (reused by pass 1) ----
  short8v af[4][4];                            // [ks][mf]
  #pragma unroll
  for (int ks = 0; ks < 4; ++ks)
    #pragma unroll
    for (int mf = 0; mf < 4; ++mf) {
      const float4* src = (const float4*)(qg + (wave*64 + mf*16 + nlo)*DIM + ks*32 + g*8);
      af[ks][mf] = pack8(src[0], src[1]);
    }

  // ---- prep: l_pos (blocks < 256, wave 0), k_mean (block 0) ----
  if (b < 256 && wave == 0) {
    const int vid = b & 63;
    float2 qv = ((const float2*)(qg + b*DIM))[lane];
    float2 kr = ((const float2*)(kg + b*DIM))[lane];
    float s0 = -kr.x, s1 = -kr.y;
    #pragma unroll
    for (int c = 0; c < 4; ++c) {
      float2 kc = ((const float2*)(kg + (vid + c*64)*DIM))[lane];
      s0 += kc.x; s1 += kc.y;
    }
    float acc = qv.x*s0 + qv.y*s1;
    #pragma unroll
    for (int off = 1; off < 64; off <<= 1) acc += __shfl_xor(acc, off, 64);
    if (lane == 0) {
      float s = exp2f(acc * (1.f/3.f) * SCL);
      sh_s = s;
      atomicAdd(&ws[WS_ROWP + (b & 31)*256 + b], s);   // fold l_pos into row sums
    }
  }
  if (b == 0) {                        // k_mean: rows 0..63 of new memory bank
    for (int j = t; j < 8192; j += 256) {
      int v = j >> 7, d = j & 127;
      ws[WS_KMEAN + j] = 0.25f * (kg[v*DIM+d] + kg[(v+64)*DIM+d] +
                                  kg[(v+128)*DIM+d] + kg[(v+192)*DIM+d]);
    }
  }
  __syncthreads();                     // kmean visible to block-0 copy below

  // ---- pass 0: read memv f32, pack bf16 in-reg, MFMA row-sums of exp ----
  float sums[4][4];
  #pragma unroll
  for (int mf = 0; mf < 4; ++mf)
    #pragma unroll
    for (int r = 0; r < 4; ++r) sums[mf][r] = 0.f;

  for (int it = 0; it < NTILES; ++it) {
    const long long n0 = (long long)b * (NTILES*32) + it*32;
    f32x4 acc[4][2];
    f32x4 zero = {0.f, 0.f, 0.f, 0.f};
    #pragma unroll
    for (int mf = 0; mf < 4; ++mf) { acc[mf][0] = zero; acc[mf][1] = zero; }

    #pragma unroll
    for (int ks = 0; ks < 4; ++ks) {
      const float4* p0 = (const float4*)(memv + (n0 + nlo)      * DIM + ks*32 + g*8);
      const float4* p1 = (const float4*)(memv + (n0 + 16 + nlo) * DIM + ks*32 + g*8);
      short8v b0 = pack8(p0[0], p0[1]);
      short8v b1 = pack8(p1[0], p1[1]);
      #pragma unroll
      for (int mf = 0; mf < 4; ++mf) {
        acc[mf][0] = __builtin_amdgcn_mfma_f32_16x16x32_bf16(af[ks][mf], b0, acc[mf][0], 0, 0, 0);
        acc[mf][1] = __builtin_amdgcn_mfma_f32_16x16x32_bf16(af[ks][mf], b1, acc[mf][1], 0, 0, 0);
      }
    }

    #pragma unroll
    for (int mf = 0; mf < 4; ++mf)
      #pragma unroll
      for (int r = 0; r < 4; ++r)
        sums[mf][r] += exp2f(acc[mf][0][r] * SCL) + exp2f(acc[mf][1][r] * SCL);
  }

  {
    float* rowp = ws + WS_ROWP + (b & 31) * 256;
    #pragma unroll
    for (int mf = 0; mf < 4; ++mf) {
      #pragma unroll
      for (int r = 0; r < 4; ++r) {
        float s = sums[mf][r];
        s += __shfl_xor(s, 1, 16);
        s += __shfl_xor(s, 2, 16);
        s += __shfl_xor(s, 4, 16);
        s += __shfl_xor(s, 8, 16);
        if (nlo == 0) atomicAdd(&rowp[wave*64 + mf*16 + g*4 + r], s);  // D: row=4g+r
      }
    }
  }

  // ---- membank copy (pre-barrier): block b copies the exact memv range it just read => L2-warm ----
  {
    float* dst = out + MEMOUT_OFF;     // odd float offset; groups at base=3+4j are 16B-aligned on dst
    const float* km = ws + WS_KMEAN;
    if (b == 0 && t == 0) {            // scalar edges
      dst[0] = km[0]; dst[1] = km[1]; dst[2] = km[2];
      dst[MEM_ELEMS - 1] = memv[MEM_ELEMS - 1];
    }
    #pragma unroll
    for (int i = 0; i < 32; ++i) {
      long long j = (long long)b * 8192 + i*256 + t;
      if (j < 4194303LL) {
        long long base = 3 + j*4;
        f32x4u v;
        if (base + 4 <= 8192) {          // kmean region (block 0 only — writer block, coherent)
          v = *(const f32x4u*)(km + base);
        } else if (base >= 8192) {
          v = *(const f32x4u*)(memv + base);
        } else {                         // straddling group (base==8191)
          float tmp[4];
          #pragma unroll
          for (int e = 0; e < 4; ++e) {
            long long idx = base + e;
            tmp[e] = (idx < 8192) ? km[idx] : memv[idx];
          }
          v.x = tmp[0]; v.y = tmp[1]; v.z = tmp[2]; v.w = tmp[3];
        }
        *(f32x4u*)(dst + base) = v;
      }
    }
  }

  // ---- device-wide spin barrier (all 512 blocks co-resident by launch_bounds) ----
  __syncthreads();
  if (t == 0) {
    unsigned* ctr = (unsigned*)ws + WS_CTR;
    __hip_atomic_fetch_add(ctr, 1u, __ATOMIC_ACQ_REL, __HIP_MEMORY_SCOPE_AGENT);
    while (__hip_atomic_load(ctr, __ATOMIC_ACQUIRE, __HIP_MEMORY_SCOPE_AGENT) < (unsigned)GRID) {
      __builtin_amdgcn_s_sleep(2);
    }
  }
  __syncthreads();

  // ---- Z: every block reduces rowp identically (bit-identical invZ everywhere) ----
  {
    float rs = 0.f;
    #pragma unroll
    for (int sl = 0; sl < 32; ++sl)
      rs += __hip_atomic_load(&ws[WS_ROWP + sl*256 + t], __ATOMIC_RELAXED, __HIP_MEMORY_SCOPE_AGENT);
    sh_rs[t] = rs;
    sh_red[t] = rs;
  }
  __syncthreads();
  for (int off = 128; off > 0; off >>= 1) {
    if (t < off) sh_red[t] += sh_red[t + off];
    __syncthreads();
  }
  float invZ;
  {
    double Z = (double)sh_red[0] * (1000000.0 / (256.0 * 131073.0));
    invZ = (float)(1.0 / Z);
  }

  if (b < 256 && t == 0) {
    out[(long long)b * CN] = sh_s * invZ;                               // out[:,0]
    atomicAdd(&out[PROBS_OFF], (sh_s / sh_rs[b]) * (1.f / 256.f));      // probs (memset to 0)
  }

  // ---- pass 1: recompute GEMM (memv now L3-warm; af still in regs), write out[:,1:] ----
  long long rowbase[4][4];
  #pragma unroll
  for (int mf = 0; mf < 4; ++mf)
    #pragma unroll
    for (int r = 0; r < 4; ++r)
      rowbase[mf][r] = (long long)(wave*64 + mf*16 + g*4 + r) * CN + 1 + nlo;

  for (int it = 0; it < NTILES; ++it) {
    const long long n0 = (long long)b * (NTILES*32) + it*32;
    f32x4 acc[4][2];
    f32x4 zero = {0.f, 0.f, 0.f, 0.f};
    #pragma unroll
    for (int mf = 0; mf < 4; ++mf) { acc[mf][0] = zero; acc[mf][1] = zero; }

    #pragma unroll
    for (int ks = 0; ks < 4; ++ks) {
      const float4* p0 = (const float4*)(memv + (n0 + nlo)      * DIM + ks*32 + g*8);
      const float4* p1 = (const float4*)(memv + (n0 + 16 + nlo) * DIM + ks*32 + g*8);
      short8v b0 = pack8(p0[0], p0[1]);
      short8v b1 = pack8(p1[0], p1[1]);
      #pragma unroll
      for (int mf = 0; mf < 4; ++mf) {
        acc[mf][0] = __builtin_amdgcn_mfma_f32_16x16x32_bf16(af[ks][mf], b0, acc[mf][0], 0, 0, 0);
        acc[mf][1] = __builtin_amdgcn_mfma_f32_16x16x32_bf16(af[ks][mf], b1, acc[mf][1], 0, 0, 0);
      }
    }

    #pragma unroll
    for (int mf = 0; mf < 4; ++mf) {
      #pragma unroll
      for (int r = 0; r < 4; ++r) {
        out[rowbase[mf][r] + n0]      = exp2f(acc[mf][0][r] * SCL) * invZ;
        out[rowbase[mf][r] + n0 + 16] = exp2f(acc[mf][1][r] * SCL) * invZ;
      }
    }
  }
}

extern "C" void kernel_launch(void* const* d_in, const int* in_sizes, int n_in,
                              void* d_out, int out_size, void* d_ws, size_t ws_size,
                              hipStream_t stream) {
  (void)in_sizes; (void)n_in; (void)out_size; (void)ws_size;
  const float* q    = (const float*)d_in[0];
  const float* k    = (const float*)d_in[1];
  const float* memv = (const float*)d_in[2];
  float* out = (float*)d_out;
  float* ws  = (float*)d_ws;

  // ws/out are poisoned 0xAA before every call: zero the accumulators the kernel needs.
  hipMemsetAsync((void*)(ws + WS_ROWP), 0, 32 * 256 * sizeof(float), stream);
  hipMemsetAsync((void*)((unsigned*)ws + WS_CTR), 0, sizeof(unsigned), stream);
  hipMemsetAsync((void*)(out + PROBS_OFF), 0, sizeof(float), stream);

  hipLaunchKernelGGL(k_mega, dim3(GRID), dim3(256), 0, stream, q, k, memv, ws, out);
}